// Round 7
// baseline (757.577 us; speedup 1.0000x reference)
//
#include <hip/hip_runtime.h>

#define NN 100000
#define NE 3200000
#define DIN 128
#define DHID 16
#define DOUT 2
#define BSH 6                // 64 dsts per bucket
#define BSZ 64
#define NBUCK ((NN + BSZ - 1) / BSZ)   // 1563
#define EPT 16               // edges per thread in hist/fill
#define BHT 1024             // threads in hist/fill blocks
#define EPB (BHT * EPT)      // 16384 edges per block
#define NBB ((NE + EPB - 1) / EPB)  // 196

// round-to-nearest-even f32 -> bf16 (bits)
__device__ __forceinline__ unsigned f2bf(float f) {
    unsigned u = __float_as_uint(f);
    return (u + 0x7FFFu + ((u >> 16) & 1u)) >> 16;
}
__device__ __forceinline__ float bflo(unsigned a) { return __uint_as_float(a << 16); }
__device__ __forceinline__ float bfhi(unsigned a) { return __uint_as_float(a & 0xFFFF0000u); }

// ---------------- bucket count zero ----------------
__global__ __launch_bounds__(1024) void k_zero_b(int* __restrict__ bcount) {
    for (int i = threadIdx.x; i < NBUCK; i += 1024) bcount[i] = 0;
}

// ---------------- coarse bucket histogram (dst >> 6) ----------------
__global__ __launch_bounds__(BHT) void k_bhist(const int* __restrict__ dst,
                                               int* __restrict__ bcount) {
    __shared__ int h[NBUCK];
    int t = threadIdx.x;
    for (int i = t; i < NBUCK; i += BHT) h[i] = 0;
    __syncthreads();
    long long base = (long long)blockIdx.x * EPB;
#pragma unroll
    for (int k = 0; k < EPT; ++k) {
        long long e = base + (long long)k * BHT + t;
        if (e < NE) atomicAdd(&h[((unsigned)dst[e]) >> BSH], 1);
    }
    __syncthreads();
    for (int i = t; i < NBUCK; i += BHT) {
        int c = h[i];
        if (c) atomicAdd(&bcount[i], c);
    }
}

// ---------------- scan 1563 bucket counts (2 per thread) ----------------
__global__ __launch_bounds__(1024) void k_bscan(const int* __restrict__ bcount,
                                                int* __restrict__ bstart,
                                                int* __restrict__ bcursor) {
    __shared__ int sc[1024];
    int t = threadIdx.x;
    int i0 = 2 * t, i1 = 2 * t + 1;
    int c0 = (i0 < NBUCK) ? bcount[i0] : 0;
    int c1 = (i1 < NBUCK) ? bcount[i1] : 0;
    int s = c0 + c1;
    sc[t] = s;
    __syncthreads();
    for (int off = 1; off < 1024; off <<= 1) {
        int v = sc[t];
        int add = (t >= off) ? sc[t - off] : 0;
        __syncthreads();
        sc[t] = v + add;
        __syncthreads();
    }
    int excl = sc[t] - s;  // exclusive prefix of pair
    if (i0 <= NBUCK) bstart[i0] = excl;
    if (i1 <= NBUCK) bstart[i1] = excl + c0;
    if (i0 < NBUCK) bcursor[i0] = excl;
    if (i1 < NBUCK) bcursor[i1] = excl + c0;
}

// ---------------- bucket the edges: packed = (dst&63)<<24 | src ------------
__global__ __launch_bounds__(BHT) void k_bfill(const int* __restrict__ src,
                                               const int* __restrict__ dst,
                                               int* __restrict__ bcursor,
                                               unsigned* __restrict__ packed) {
    __shared__ int h[NBUCK];     // local hist, then local cursor
    __shared__ int hbase[NBUCK]; // reserved global base per bucket
    int t = threadIdx.x;
    for (int i = t; i < NBUCK; i += BHT) h[i] = 0;
    __syncthreads();
    long long base = (long long)blockIdx.x * EPB;
    int ed[EPT], es[EPT];
#pragma unroll
    for (int k = 0; k < EPT; ++k) {
        long long e = base + (long long)k * BHT + t;
        if (e < NE) {
            ed[k] = dst[e];
            es[k] = src[e];
            atomicAdd(&h[((unsigned)ed[k]) >> BSH], 1);
        } else {
            ed[k] = -1;
            es[k] = 0;
        }
    }
    __syncthreads();
    for (int i = t; i < NBUCK; i += BHT) {
        int c = h[i];
        hbase[i] = c ? atomicAdd(&bcursor[i], c) : 0;
    }
    __syncthreads();
    for (int i = t; i < NBUCK; i += BHT) h[i] = 0;
    __syncthreads();
#pragma unroll
    for (int k = 0; k < EPT; ++k) {
        if (ed[k] >= 0) {
            unsigned d = (unsigned)ed[k];
            int b = d >> BSH;
            int off = atomicAdd(&h[b], 1);
            packed[hbase[b] + off] = ((d & (BSZ - 1u)) << 24) | (unsigned)es[k];
        }
    }
}

// ---------------- per-bucket degree -> dinv ----------------
__global__ __launch_bounds__(256) void k_dinvb(const int* __restrict__ bstart,
                                               const unsigned* __restrict__ packed,
                                               float* __restrict__ dinv) {
    __shared__ int h[BSZ];
    int b = blockIdx.x;
    int t = threadIdx.x;
    if (t < BSZ) h[t] = 0;
    __syncthreads();
    int ebeg = bstart[b], eend = bstart[b + 1];
    for (int e = ebeg + t; e < eend; e += 256)
        atomicAdd(&h[(packed[e] >> 24) & (BSZ - 1)], 1);
    __syncthreads();
    int v = (b << BSH) + t;
    if (t < BSZ && v < NN) dinv[v] = rsqrtf((float)(h[t] + 1));
}

// ---------------- layer 1 transform: DPP quad-perm, 2 nodes/thread --------
// Quad-pos q owns channels 4q..4q+3 and x-quarter [q*32,q*32+32) of both its
// nodes. x values broadcast within the quad via DPP; W via broadcast
// ds_read_b128 (4 distinct addrs/wave, distinct banks -> conflict-free).
__global__ __launch_bounds__(256) void k_mm1(const float* __restrict__ x,
                                             const float* __restrict__ W1,
                                             const float* __restrict__ dinv,
                                             unsigned* __restrict__ g1b) {
    __shared__ float Ws[DIN * DHID];  // 8 KB
    for (int i = threadIdx.x; i < DIN * DHID; i += 256) Ws[i] = W1[i];
    __syncthreads();
    const float4* Ws4 = (const float4*)Ws;
    int t = threadIdx.x;
    int q = t & 3;
    int vA = blockIdx.x * 128 + ((t >> 6) << 5) + ((t & 63) >> 2);  // wave base + lane group
    int vB = vA + 16;
    int rA = (vA < NN) ? vA : NN - 1;
    int rB = (vB < NN) ? vB : NN - 1;
    float4 xqA[8], xqB[8];
    const float4* xrA = (const float4*)(x + (size_t)rA * DIN + q * 32);
    const float4* xrB = (const float4*)(x + (size_t)rB * DIN + q * 32);
#pragma unroll
    for (int i = 0; i < 8; ++i) { xqA[i] = xrA[i]; xqB[i] = xrB[i]; }
    const float* xsA = (const float*)xqA;
    const float* xsB = (const float*)xqB;
    float a0 = 0.f, a1 = 0.f, a2 = 0.f, a3 = 0.f;
    float b0 = 0.f, b1v = 0.f, b2v = 0.f, b3 = 0.f;
#define QSTEP(QQ, CTRL)                                                           \
    _Pragma("unroll")                                                             \
    for (int k = 0; k < 32; ++k) {                                                \
        float xvA = __int_as_float(                                               \
            __builtin_amdgcn_mov_dpp(__float_as_int(xsA[k]), CTRL, 0xF, 0xF, false)); \
        float xvB = __int_as_float(                                               \
            __builtin_amdgcn_mov_dpp(__float_as_int(xsB[k]), CTRL, 0xF, 0xF, false)); \
        const float4 w = Ws4[(QQ * 32 + k) * 4 + q];                              \
        a0 += xvA * w.x; a1 += xvA * w.y; a2 += xvA * w.z; a3 += xvA * w.w;        \
        b0 += xvB * w.x; b1v += xvB * w.y; b2v += xvB * w.z; b3 += xvB * w.w;      \
    }
    QSTEP(0, 0x00)
    QSTEP(1, 0x55)
    QSTEP(2, 0xAA)
    QSTEP(3, 0xFF)
#undef QSTEP
    if (vA < NN) {
        float dv = dinv[vA];
        ((uint2*)(g1b + (size_t)vA * 8))[q] =
            make_uint2(f2bf(a0 * dv) | (f2bf(a1 * dv) << 16),
                       f2bf(a2 * dv) | (f2bf(a3 * dv) << 16));
    }
    if (vB < NN) {
        float dv = dinv[vB];
        ((uint2*)(g1b + (size_t)vB * 8))[q] =
            make_uint2(f2bf(b0 * dv) | (f2bf(b1v * dv) << 16),
                       f2bf(b2v * dv) | (f2bf(b3 * dv) << 16));
    }
}

// ---------------- fused layer-1 gather + layer-2 transform -----------------
// One block per bucket. acc[64][16] f32 in LDS (pad 17). 8 lanes/edge,
// lane j owns channels 2j,2j+1; ds_add_f32 accumulation; 2x unroll for MLP.
__global__ __launch_bounds__(256) void k_gth1(const int* __restrict__ bstart,
                                              const unsigned* __restrict__ packed,
                                              const float* __restrict__ dinv,
                                              const unsigned* __restrict__ G,
                                              const float* __restrict__ b1,
                                              const float* __restrict__ W2,
                                              float* __restrict__ g2) {
    __shared__ float accs[BSZ][17];
    int b = blockIdx.x;
    int t = threadIdx.x;
    int v0 = b << BSH;
    if (t < 128) {  // self-loop init: 2 threads/dst, 8 ch each
        int dl = t >> 1, half = t & 1;
        int v = v0 + dl;
        if (v < NN) {
            uint4 gr = *(const uint4*)(G + ((size_t)v << 3) + half * 4);
            accs[dl][half * 8 + 0] = bflo(gr.x);
            accs[dl][half * 8 + 1] = bfhi(gr.x);
            accs[dl][half * 8 + 2] = bflo(gr.y);
            accs[dl][half * 8 + 3] = bfhi(gr.y);
            accs[dl][half * 8 + 4] = bflo(gr.z);
            accs[dl][half * 8 + 5] = bfhi(gr.z);
            accs[dl][half * 8 + 6] = bflo(gr.w);
            accs[dl][half * 8 + 7] = bfhi(gr.w);
        } else {
#pragma unroll
            for (int i = 0; i < 8; ++i) accs[dl][half * 8 + i] = 0.f;
        }
    }
    __syncthreads();
    int ebeg = bstart[b], eend = bstart[b + 1];
    int slot = t >> 3, j = t & 7;
    int e = ebeg + slot;
    for (; e + 32 < eend; e += 64) {
        unsigned pk0 = packed[e];
        unsigned pk1 = packed[e + 32];
        unsigned g0 = G[((size_t)(pk0 & 0xFFFFFFu) << 3) + j];
        unsigned g1 = G[((size_t)(pk1 & 0xFFFFFFu) << 3) + j];
        int dl0 = (pk0 >> 24) & (BSZ - 1);
        int dl1 = (pk1 >> 24) & (BSZ - 1);
        atomicAdd(&accs[dl0][2 * j], bflo(g0));
        atomicAdd(&accs[dl0][2 * j + 1], bfhi(g0));
        atomicAdd(&accs[dl1][2 * j], bflo(g1));
        atomicAdd(&accs[dl1][2 * j + 1], bfhi(g1));
    }
    if (e < eend) {
        unsigned pk0 = packed[e];
        unsigned g0 = G[((size_t)(pk0 & 0xFFFFFFu) << 3) + j];
        int dl0 = (pk0 >> 24) & (BSZ - 1);
        atomicAdd(&accs[dl0][2 * j], bflo(g0));
        atomicAdd(&accs[dl0][2 * j + 1], bfhi(g0));
    }
    __syncthreads();
    if (t < BSZ) {  // epilogue: out1 scale, relu+b1, @W2, scale -> g2
        int v = v0 + t;
        if (v < NN) {
            float dv = dinv[v];
            float p0 = 0.f, p1 = 0.f;
#pragma unroll
            for (int ch = 0; ch < 16; ++ch) {
                float o = fmaxf(accs[t][ch] * dv + b1[ch], 0.f);
                p0 += o * W2[ch * 2 + 0];
                p1 += o * W2[ch * 2 + 1];
            }
            *(float2*)(g2 + (size_t)v * 2) = make_float2(p0 * dv, p1 * dv);
        }
    }
}

// ---------------- fused layer-2 gather + bias + log_softmax ----------------
__global__ __launch_bounds__(256) void k_gth2(const int* __restrict__ bstart,
                                              const unsigned* __restrict__ packed,
                                              const float* __restrict__ dinv,
                                              const float* __restrict__ g2,
                                              const float* __restrict__ b2,
                                              float* __restrict__ out) {
    __shared__ float acc2[BSZ][3];
    int b = blockIdx.x;
    int t = threadIdx.x;
    int v0 = b << BSH;
    if (t < BSZ) {  // self loop
        int v = v0 + t;
        float2 s = (v < NN) ? *(const float2*)(g2 + (size_t)v * 2)
                            : make_float2(0.f, 0.f);
        acc2[t][0] = s.x;
        acc2[t][1] = s.y;
    }
    __syncthreads();
    int ebeg = bstart[b], eend = bstart[b + 1];
    int e = ebeg + t;
    for (; e + 256 < eend; e += 512) {
        unsigned pk0 = packed[e];
        unsigned pk1 = packed[e + 256];
        float2 s0 = *(const float2*)(g2 + ((size_t)(pk0 & 0xFFFFFFu) << 1));
        float2 s1 = *(const float2*)(g2 + ((size_t)(pk1 & 0xFFFFFFu) << 1));
        int dl0 = (pk0 >> 24) & (BSZ - 1);
        int dl1 = (pk1 >> 24) & (BSZ - 1);
        atomicAdd(&acc2[dl0][0], s0.x);
        atomicAdd(&acc2[dl0][1], s0.y);
        atomicAdd(&acc2[dl1][0], s1.x);
        atomicAdd(&acc2[dl1][1], s1.y);
    }
    if (e < eend) {
        unsigned pk0 = packed[e];
        float2 s0 = *(const float2*)(g2 + ((size_t)(pk0 & 0xFFFFFFu) << 1));
        int dl0 = (pk0 >> 24) & (BSZ - 1);
        atomicAdd(&acc2[dl0][0], s0.x);
        atomicAdd(&acc2[dl0][1], s0.y);
    }
    __syncthreads();
    if (t < BSZ) {
        int v = v0 + t;
        if (v < NN) {
            float dv = dinv[v];
            float a0 = acc2[t][0] * dv + b2[0];
            float a1 = acc2[t][1] * dv + b2[1];
            float m = fmaxf(a0, a1);
            float lse = m + logf(expf(a0 - m) + expf(a1 - m));
            *(float2*)(out + (size_t)v * 2) = make_float2(a0 - lse, a1 - lse);
        }
    }
}

extern "C" void kernel_launch(void* const* d_in, const int* in_sizes, int n_in,
                              void* d_out, int out_size, void* d_ws, size_t ws_size,
                              hipStream_t stream) {
    const float* x  = (const float*)d_in[0];
    const float* W1 = (const float*)d_in[1];
    const float* b1 = (const float*)d_in[2];
    const float* W2 = (const float*)d_in[3];
    const float* b2 = (const float*)d_in[4];
    const int* ei   = (const int*)d_in[5];
    const int* src = ei;
    const int* dst = ei + NE;

    // workspace (4B elems); no aliasing this round (packed stays live).
    int* ws       = (int*)d_ws;
    int* bcount   = ws;                    // 1600
    int* bstart   = ws + 1600;             // 1600 (uses NBUCK+1)
    int* bcursor  = ws + 3200;             // 1600
    float* dinv   = (float*)(ws + 4800);   // NN
    unsigned* packed = (unsigned*)(ws + 4800 + NN);   // NE
    unsigned* g1b = packed + NE;           // 8*NN (16B-aligned)
    float* g2     = (float*)(g1b + 8 * NN); // 2*NN

    float* out = (float*)d_out;

    k_zero_b<<<1, 1024, 0, stream>>>(bcount);
    k_bhist<<<NBB, BHT, 0, stream>>>(dst, bcount);
    k_bscan<<<1, 1024, 0, stream>>>(bcount, bstart, bcursor);
    k_bfill<<<NBB, BHT, 0, stream>>>(src, dst, bcursor, packed);
    k_dinvb<<<NBUCK, 256, 0, stream>>>(bstart, packed, dinv);
    k_mm1<<<(NN + 127) / 128, 256, 0, stream>>>(x, W1, dinv, g1b);
    k_gth1<<<NBUCK, 256, 0, stream>>>(bstart, packed, dinv, g1b, b1, W2, g2);
    k_gth2<<<NBUCK, 256, 0, stream>>>(bstart, packed, dinv, g2, b2, out);
}

// Round 8
// 484.379 us; speedup vs baseline: 1.5640x; 1.5640x over previous
//
#include <hip/hip_runtime.h>

#define NN 100000
#define NE 3200000
#define DIN 128
#define DHID 16
#define DOUT 2
#define NBUCK 391            // ceil(NN/256) buckets of 256 dst nodes
#define EPT 16               // edges per thread in hist/fill
#define BHT 1024             // threads in hist/fill blocks
#define EPB (BHT * EPT)      // 16384 edges per block
#define NBB ((NE + EPB - 1) / EPB)  // 196

// round-to-nearest-even f32 -> bf16 (bits)
__device__ __forceinline__ unsigned f2bf(float f) {
    unsigned u = __float_as_uint(f);
    return (u + 0x7FFFu + ((u >> 16) & 1u)) >> 16;
}
__device__ __forceinline__ float bflo(unsigned a) { return __uint_as_float(a << 16); }
__device__ __forceinline__ float bfhi(unsigned a) { return __uint_as_float(a & 0xFFFF0000u); }

// ---------------- bucket count zero ----------------
__global__ __launch_bounds__(512) void k_zero_b(int* __restrict__ bcount) {
    int t = threadIdx.x;
    if (t < NBUCK) bcount[t] = 0;
}

// ---------------- coarse bucket histogram (dst >> 8) ----------------
__global__ __launch_bounds__(BHT) void k_bhist(const int* __restrict__ dst,
                                               int* __restrict__ bcount) {
    __shared__ int h[NBUCK];
    int t = threadIdx.x;
    for (int i = t; i < NBUCK; i += BHT) h[i] = 0;
    __syncthreads();
    long long base = (long long)blockIdx.x * EPB;
#pragma unroll
    for (int k = 0; k < EPT; ++k) {
        long long e = base + (long long)k * BHT + t;
        if (e < NE) atomicAdd(&h[((unsigned)dst[e]) >> 8], 1);
    }
    __syncthreads();
    for (int i = t; i < NBUCK; i += BHT) {
        int c = h[i];
        if (c) atomicAdd(&bcount[i], c);
    }
}

// ---------------- scan 391 bucket counts ----------------
__global__ __launch_bounds__(512) void k_bscan(const int* __restrict__ bcount,
                                               int* __restrict__ bstart,
                                               int* __restrict__ bcursor) {
    __shared__ int sc[512];
    int t = threadIdx.x;
    int c = (t < NBUCK) ? bcount[t] : 0;
    sc[t] = c;
    __syncthreads();
    for (int off = 1; off < 512; off <<= 1) {
        int v = sc[t];
        int add = (t >= off) ? sc[t - off] : 0;
        __syncthreads();
        sc[t] = v + add;
        __syncthreads();
    }
    int excl = sc[t] - c;
    if (t <= NBUCK) bstart[t] = excl;  // bstart[NBUCK] == NE
    if (t < NBUCK) bcursor[t] = excl;
}

// ---------------- bucket the edges: packed = (dstLow<<24)|src ----------------
__global__ __launch_bounds__(BHT) void k_bfill(const int* __restrict__ src,
                                               const int* __restrict__ dst,
                                               int* __restrict__ bcursor,
                                               unsigned* __restrict__ packed) {
    __shared__ int h[NBUCK];     // local hist, then local cursor
    __shared__ int hbase[NBUCK]; // reserved global base per bucket
    int t = threadIdx.x;
    for (int i = t; i < NBUCK; i += BHT) h[i] = 0;
    __syncthreads();
    long long base = (long long)blockIdx.x * EPB;
    int ed[EPT], es[EPT];
#pragma unroll
    for (int k = 0; k < EPT; ++k) {
        long long e = base + (long long)k * BHT + t;
        if (e < NE) {
            ed[k] = dst[e];
            es[k] = src[e];
            atomicAdd(&h[((unsigned)ed[k]) >> 8], 1);
        } else {
            ed[k] = -1;
            es[k] = 0;
        }
    }
    __syncthreads();
    for (int i = t; i < NBUCK; i += BHT) {
        int c = h[i];
        hbase[i] = c ? atomicAdd(&bcursor[i], c) : 0;
    }
    __syncthreads();
    for (int i = t; i < NBUCK; i += BHT) h[i] = 0;
    __syncthreads();
#pragma unroll
    for (int k = 0; k < EPT; ++k) {
        if (ed[k] >= 0) {
            unsigned d = (unsigned)ed[k];
            int b = d >> 8;
            int off = atomicAdd(&h[b], 1);
            packed[hbase[b] + off] = ((d & 255u) << 24) | (unsigned)es[k];
        }
    }
}

// ---------------- per-bucket exact sort -> rowstart, dinv, esrc ----------------
__global__ __launch_bounds__(256) void k_pass2(const int* __restrict__ bstart,
                                               const unsigned* __restrict__ packed,
                                               int* __restrict__ rowstart,
                                               float* __restrict__ dinv,
                                               int* __restrict__ esrc) {
    __shared__ int h[256], sc[256], cur[256];
    int b = blockIdx.x;
    int t = threadIdx.x;
    int dst0 = b << 8;
    int ebeg = bstart[b];
    int eend = bstart[b + 1];
    h[t] = 0;
    __syncthreads();
    for (int p = ebeg + t; p < eend; p += 256)
        atomicAdd(&h[packed[p] >> 24], 1);
    __syncthreads();
    int c = h[t];
    sc[t] = c;
    __syncthreads();
    for (int off = 1; off < 256; off <<= 1) {
        int v = sc[t];
        int add = (t >= off) ? sc[t - off] : 0;
        __syncthreads();
        sc[t] = v + add;
        __syncthreads();
    }
    int gpos = ebeg + sc[t] - c;
    int v = dst0 + t;
    if (v < NN) {
        rowstart[v] = gpos;
        dinv[v] = rsqrtf((float)(c + 1));
    }
    cur[t] = gpos;
    if (b == 0 && t == 0) rowstart[NN] = NE;
    __syncthreads();
    for (int p = ebeg + t; p < eend; p += 256) {
        unsigned pk = packed[p];
        int pos = atomicAdd(&cur[pk >> 24], 1);
        esrc[pos] = (int)(pk & 0xFFFFFFu);
    }
}

// ---------------- layer 1 transform: DPP quad-perm, 2 nodes/thread --------
// Quad-pos q owns channels 4q..4q+3 and x-quarter [q*32,q*32+32) of both its
// nodes (vA, vB = vA+64). ALL array indices are compile-time constants
// (explicit .x/.y/.z/.w macros, no pointer casts) so xA/xB stay in VGPRs
// (R6 lesson: casted-pointer reads sent them to scratch, 429 MB spill).
__global__ __launch_bounds__(256) void k_mm1(const float* __restrict__ x,
                                             const float* __restrict__ W1,
                                             const float* __restrict__ dinv,
                                             unsigned* __restrict__ g1b) {
    __shared__ float Ws[DIN * DHID];  // 8 KB
    for (int i = threadIdx.x; i < DIN * DHID; i += 256) Ws[i] = W1[i];
    __syncthreads();
    const float4* Ws4 = (const float4*)Ws;
    int t = threadIdx.x;
    int q = t & 3;
    int vA = blockIdx.x * 128 + (t >> 2);  // nodes 0..63 of this block
    int vB = vA + 64;                      // nodes 64..127
    int rA = (vA < NN) ? vA : NN - 1;
    int rB = (vB < NN) ? vB : NN - 1;
    float4 xA[8], xB[8];
    const float4* pA = (const float4*)(x + (size_t)rA * DIN + q * 32);
    const float4* pB = (const float4*)(x + (size_t)rB * DIN + q * 32);
#pragma unroll
    for (int i = 0; i < 8; ++i) { xA[i] = pA[i]; xB[i] = pB[i]; }
    float a0 = 0.f, a1 = 0.f, a2 = 0.f, a3 = 0.f;
    float b0 = 0.f, b1v = 0.f, b2v = 0.f, b3 = 0.f;
#define ACC1(QQ, CTRL, I, COMP, KK)                                               \
    {                                                                             \
        float xvA = __int_as_float(__builtin_amdgcn_mov_dpp(                      \
            __float_as_int(xA[I].COMP), CTRL, 0xF, 0xF, false));                  \
        float xvB = __int_as_float(__builtin_amdgcn_mov_dpp(                      \
            __float_as_int(xB[I].COMP), CTRL, 0xF, 0xF, false));                  \
        const float4 w = Ws4[(QQ * 32 + (KK)) * 4 + q];                           \
        a0 = fmaf(xvA, w.x, a0); a1 = fmaf(xvA, w.y, a1);                         \
        a2 = fmaf(xvA, w.z, a2); a3 = fmaf(xvA, w.w, a3);                         \
        b0 = fmaf(xvB, w.x, b0); b1v = fmaf(xvB, w.y, b1v);                       \
        b2v = fmaf(xvB, w.z, b2v); b3 = fmaf(xvB, w.w, b3);                       \
    }
#define ACC4(QQ, CTRL, I)          \
    ACC1(QQ, CTRL, I, x, I * 4 + 0) \
    ACC1(QQ, CTRL, I, y, I * 4 + 1) \
    ACC1(QQ, CTRL, I, z, I * 4 + 2) \
    ACC1(QQ, CTRL, I, w, I * 4 + 3)
#define QST(QQ, CTRL)     \
    ACC4(QQ, CTRL, 0) ACC4(QQ, CTRL, 1) ACC4(QQ, CTRL, 2) ACC4(QQ, CTRL, 3) \
    ACC4(QQ, CTRL, 4) ACC4(QQ, CTRL, 5) ACC4(QQ, CTRL, 6) ACC4(QQ, CTRL, 7)
    QST(0, 0x00)
    QST(1, 0x55)
    QST(2, 0xAA)
    QST(3, 0xFF)
#undef QST
#undef ACC4
#undef ACC1
    if (vA < NN) {
        float dv = dinv[vA];
        ((uint2*)(g1b + (size_t)vA * 8))[q] =
            make_uint2(f2bf(a0 * dv) | (f2bf(a1 * dv) << 16),
                       f2bf(a2 * dv) | (f2bf(a3 * dv) << 16));
    }
    if (vB < NN) {
        float dv = dinv[vB];
        ((uint2*)(g1b + (size_t)vB * 8))[q] =
            make_uint2(f2bf(b0 * dv) | (f2bf(b1v * dv) << 16),
                       f2bf(b2v * dv) | (f2bf(b3 * dv) << 16));
    }
}

// ---------------- layer 1 gather + fused layer-2 transform ----------------
// 8 lanes/node; lane j owns channels 2j,2j+1. After the gather, each lane
// applies relu+b1 and its W2 rows, then 3 shfl_xor reduce -> g2.
__global__ __launch_bounds__(256) void k_gather1mm2(const int* __restrict__ rowstart,
                                                    const int* __restrict__ esrc,
                                                    const float* __restrict__ dinv,
                                                    const unsigned* __restrict__ G,
                                                    const float* __restrict__ b1,
                                                    const float* __restrict__ W2,
                                                    float* __restrict__ g2) {
    int t = blockIdx.x * 256 + threadIdx.x;
    int v = t >> 3;
    int j = t & 7;
    if (v >= NN) return;
    int beg = rowstart[v];
    int end = rowstart[v + 1];
    unsigned a = G[(v << 3) + j];  // self loop
    float c0 = bflo(a), c1 = bfhi(a);
    int p = beg;
    int n4 = beg + ((end - beg) & ~3);
    for (; p < n4; p += 4) {
        int u0 = esrc[p], u1 = esrc[p + 1], u2 = esrc[p + 2], u3 = esrc[p + 3];
        unsigned b0 = G[(u0 << 3) + j];
        unsigned b1w = G[(u1 << 3) + j];
        unsigned b2w = G[(u2 << 3) + j];
        unsigned b3w = G[(u3 << 3) + j];
        c0 += bflo(b0) + bflo(b1w) + bflo(b2w) + bflo(b3w);
        c1 += bfhi(b0) + bfhi(b1w) + bfhi(b2w) + bfhi(b3w);
    }
    for (; p < end; ++p) {
        unsigned b = G[(esrc[p] << 3) + j];
        c0 += bflo(b);
        c1 += bfhi(b);
    }
    float dv = dinv[v];
    // fused mm2: relu(out1 + b1) @ W2, partial over this lane's 2 channels
    float o0 = fmaxf(c0 * dv + b1[2 * j], 0.f);
    float o1 = fmaxf(c1 * dv + b1[2 * j + 1], 0.f);
    float p0 = o0 * W2[(2 * j) * 2 + 0] + o1 * W2[(2 * j + 1) * 2 + 0];
    float p1 = o0 * W2[(2 * j) * 2 + 1] + o1 * W2[(2 * j + 1) * 2 + 1];
    p0 += __shfl_xor(p0, 1); p0 += __shfl_xor(p0, 2); p0 += __shfl_xor(p0, 4);
    p1 += __shfl_xor(p1, 1); p1 += __shfl_xor(p1, 2); p1 += __shfl_xor(p1, 4);
    if (j == 0) {
        float2 w = make_float2(p0 * dv, p1 * dv);
        *(float2*)(g2 + (size_t)v * 2) = w;
    }
}

// ---------------- layer 2 gather: 8 lanes/node = 4 edge-slots x 2 ch -------
__global__ __launch_bounds__(256) void k_gather2(const int* __restrict__ rowstart,
                                                 const int* __restrict__ esrc,
                                                 const float* __restrict__ dinv,
                                                 const float* __restrict__ g2,
                                                 const float* __restrict__ b2,
                                                 float* __restrict__ out) {
    int t = blockIdx.x * 256 + threadIdx.x;
    int v = t >> 3;
    if (v >= NN) return;
    int lane = t & 7;
    int ch = lane & 1;
    int slot = lane >> 1;
    int beg = rowstart[v];
    int end = rowstart[v + 1];
    float acc = 0.0f;
    for (int p = beg + slot; p < end; p += 4)
        acc += g2[(esrc[p] << 1) + ch];
    acc += __shfl_xor(acc, 2);
    acc += __shfl_xor(acc, 4);  // all slots summed
    float o = (acc + g2[(v << 1) + ch]) * dinv[v] + b2[ch];
    float other = __shfl_xor(o, 1);
    float m = fmaxf(o, other);
    float lse = m + logf(expf(o - m) + expf(other - m));
    if (slot == 0) out[(v << 1) + ch] = o - lse;
}

extern "C" void kernel_launch(void* const* d_in, const int* in_sizes, int n_in,
                              void* d_out, int out_size, void* d_ws, size_t ws_size,
                              hipStream_t stream) {
    const float* x  = (const float*)d_in[0];
    const float* W1 = (const float*)d_in[1];
    const float* b1 = (const float*)d_in[2];
    const float* W2 = (const float*)d_in[3];
    const float* b2 = (const float*)d_in[4];
    const int* ei   = (const int*)d_in[5];
    const int* src = ei;
    const int* dst = ei + NE;

    // workspace (4B elems). packed (NE=12.8MB) is dead after k_pass2;
    // g1b (8NN uints = 3.2MB) aliases it. Stream order makes this safe.
    int* ws       = (int*)d_ws;
    int* bcount   = ws;                    // 400
    int* bstart   = ws + 400;              // 400 (uses NBUCK+1)
    int* bcursor  = ws + 800;              // 400
    int* rowstart = ws + 1200;             // NN+16
    float* dinv   = (float*)(ws + 1200 + NN + 16);    // NN
    int* esrc     = ws + 1200 + 2 * NN + 16;          // NE
    unsigned* packed = (unsigned*)(esrc + NE);        // NE
    unsigned* g1b = packed;                // 8*NN uints (aliases packed)
    float* g2     = (float*)(packed + NE); // 2*NN

    float* out = (float*)d_out;

    k_zero_b<<<1, 512, 0, stream>>>(bcount);
    k_bhist<<<NBB, BHT, 0, stream>>>(dst, bcount);
    k_bscan<<<1, 512, 0, stream>>>(bcount, bstart, bcursor);
    k_bfill<<<NBB, BHT, 0, stream>>>(src, dst, bcursor, packed);
    k_pass2<<<NBUCK, 256, 0, stream>>>(bstart, packed, rowstart, dinv, esrc);
    k_mm1<<<(NN + 127) / 128, 256, 0, stream>>>(x, W1, dinv, g1b);
    k_gather1mm2<<<(NN * 8 + 255) / 256, 256, 0, stream>>>(rowstart, esrc, dinv, g1b, b1, W2, g2);
    k_gather2<<<(NN * 8 + 255) / 256, 256, 0, stream>>>(rowstart, esrc, dinv, g2, b2, out);
}

// Round 9
// 140.017 us; speedup vs baseline: 5.4106x; 3.4594x over previous
//
#include <hip/hip_runtime.h>

#define NN 100000
#define NE 3200000
#define DIN 128
#define DHID 16
#define DOUT 2
#define NBUCK 391            // ceil(NN/256) buckets of 256 dst nodes
#define EPT 16               // edges per thread in hist/fill
#define BHT 1024             // threads in hist/fill blocks
#define EPB (BHT * EPT)      // 16384 edges per block
#define NBB ((NE + EPB - 1) / EPB)  // 196

// round-to-nearest-even f32 -> bf16 (bits)
__device__ __forceinline__ unsigned f2bf(float f) {
    unsigned u = __float_as_uint(f);
    return (u + 0x7FFFu + ((u >> 16) & 1u)) >> 16;
}
__device__ __forceinline__ float bflo(unsigned a) { return __uint_as_float(a << 16); }
__device__ __forceinline__ float bfhi(unsigned a) { return __uint_as_float(a & 0xFFFF0000u); }

// ---------------- bucket count zero ----------------
__global__ __launch_bounds__(512) void k_zero_b(int* __restrict__ bcount) {
    int t = threadIdx.x;
    if (t < NBUCK) bcount[t] = 0;
}

// ---------------- coarse bucket histogram (dst >> 8) ----------------
__global__ __launch_bounds__(BHT) void k_bhist(const int* __restrict__ dst,
                                               int* __restrict__ bcount) {
    __shared__ int h[NBUCK];
    int t = threadIdx.x;
    for (int i = t; i < NBUCK; i += BHT) h[i] = 0;
    __syncthreads();
    long long base = (long long)blockIdx.x * EPB;
#pragma unroll
    for (int k = 0; k < EPT; ++k) {
        long long e = base + (long long)k * BHT + t;
        if (e < NE) atomicAdd(&h[((unsigned)dst[e]) >> 8], 1);
    }
    __syncthreads();
    for (int i = t; i < NBUCK; i += BHT) {
        int c = h[i];
        if (c) atomicAdd(&bcount[i], c);
    }
}

// ---------------- scan 391 bucket counts ----------------
__global__ __launch_bounds__(512) void k_bscan(const int* __restrict__ bcount,
                                               int* __restrict__ bstart,
                                               int* __restrict__ bcursor) {
    __shared__ int sc[512];
    int t = threadIdx.x;
    int c = (t < NBUCK) ? bcount[t] : 0;
    sc[t] = c;
    __syncthreads();
    for (int off = 1; off < 512; off <<= 1) {
        int v = sc[t];
        int add = (t >= off) ? sc[t - off] : 0;
        __syncthreads();
        sc[t] = v + add;
        __syncthreads();
    }
    int excl = sc[t] - c;
    if (t <= NBUCK) bstart[t] = excl;  // bstart[NBUCK] == NE
    if (t < NBUCK) bcursor[t] = excl;
}

// ---------------- bucket the edges: packed = (dstLow<<24)|src ----------------
__global__ __launch_bounds__(BHT) void k_bfill(const int* __restrict__ src,
                                               const int* __restrict__ dst,
                                               int* __restrict__ bcursor,
                                               unsigned* __restrict__ packed) {
    __shared__ int h[NBUCK];     // local hist, then local cursor
    __shared__ int hbase[NBUCK]; // reserved global base per bucket
    int t = threadIdx.x;
    for (int i = t; i < NBUCK; i += BHT) h[i] = 0;
    __syncthreads();
    long long base = (long long)blockIdx.x * EPB;
    int ed[EPT], es[EPT];
#pragma unroll
    for (int k = 0; k < EPT; ++k) {
        long long e = base + (long long)k * BHT + t;
        if (e < NE) {
            ed[k] = dst[e];
            es[k] = src[e];
            atomicAdd(&h[((unsigned)ed[k]) >> 8], 1);
        } else {
            ed[k] = -1;
            es[k] = 0;
        }
    }
    __syncthreads();
    for (int i = t; i < NBUCK; i += BHT) {
        int c = h[i];
        hbase[i] = c ? atomicAdd(&bcursor[i], c) : 0;
    }
    __syncthreads();
    for (int i = t; i < NBUCK; i += BHT) h[i] = 0;
    __syncthreads();
#pragma unroll
    for (int k = 0; k < EPT; ++k) {
        if (ed[k] >= 0) {
            unsigned d = (unsigned)ed[k];
            int b = d >> 8;
            int off = atomicAdd(&h[b], 1);
            packed[hbase[b] + off] = ((d & 255u) << 24) | (unsigned)es[k];
        }
    }
}

// ---------------- per-bucket exact sort -> rowstart, dinv, esrc ----------------
__global__ __launch_bounds__(256) void k_pass2(const int* __restrict__ bstart,
                                               const unsigned* __restrict__ packed,
                                               int* __restrict__ rowstart,
                                               float* __restrict__ dinv,
                                               int* __restrict__ esrc) {
    __shared__ int h[256], sc[256], cur[256];
    int b = blockIdx.x;
    int t = threadIdx.x;
    int dst0 = b << 8;
    int ebeg = bstart[b];
    int eend = bstart[b + 1];
    h[t] = 0;
    __syncthreads();
    for (int p = ebeg + t; p < eend; p += 256)
        atomicAdd(&h[packed[p] >> 24], 1);
    __syncthreads();
    int c = h[t];
    sc[t] = c;
    __syncthreads();
    for (int off = 1; off < 256; off <<= 1) {
        int v = sc[t];
        int add = (t >= off) ? sc[t - off] : 0;
        __syncthreads();
        sc[t] = v + add;
        __syncthreads();
    }
    int gpos = ebeg + sc[t] - c;
    int v = dst0 + t;
    if (v < NN) {
        rowstart[v] = gpos;
        dinv[v] = rsqrtf((float)(c + 1));
    }
    cur[t] = gpos;
    if (b == 0 && t == 0) rowstart[NN] = NE;
    __syncthreads();
    for (int p = ebeg + t; p < eend; p += 256) {
        unsigned pk = packed[p];
        int pos = atomicAdd(&cur[pk >> 24], 1);
        esrc[pos] = (int)(pk & 0xFFFFFFu);
    }
}

// ---------------- layer 1 transform: 4 lanes/node, 4 channels/lane ----------
// R4-verbatim (proven no-spill). Lane q loads x-row quarter [q*32,q*32+32);
// x values broadcast within the quad via DPP quad-perm; W row-chunk via
// broadcast ds_read_b128. Channels lane-owned; no cross-lane reduction.
__global__ __launch_bounds__(256) void k_mm1(const float* __restrict__ x,
                                             const float* __restrict__ W1,
                                             const float* __restrict__ dinv,
                                             unsigned* __restrict__ g1b) {
    __shared__ float Ws[DIN * DHID];  // 8 KB
    for (int i = threadIdx.x; i < DIN * DHID; i += 256) Ws[i] = W1[i];
    __syncthreads();
    int t = blockIdx.x * 256 + threadIdx.x;
    int v = t >> 2;
    int q = threadIdx.x & 3;
    if (v >= NN) return;
    float4 xq[8];
    const float4* xr = (const float4*)(x + (size_t)v * DIN + q * 32);
#pragma unroll
    for (int i = 0; i < 8; ++i) xq[i] = xr[i];
    const float* xs = (const float*)xq;
    float acc0 = 0.f, acc1 = 0.f, acc2 = 0.f, acc3 = 0.f;
    // quad-perm broadcast from quad-lane QQ: dpp_ctrl = QQ * 0x55
#define QSTEP(QQ, CTRL)                                                          \
    _Pragma("unroll")                                                            \
    for (int k = 0; k < 32; ++k) {                                               \
        float xv = __int_as_float(                                               \
            __builtin_amdgcn_mov_dpp(__float_as_int(xs[k]), CTRL, 0xF, 0xF, false)); \
        const float4 w = *(const float4*)&Ws[(QQ * 32 + k) * DHID + q * 4];      \
        acc0 += xv * w.x; acc1 += xv * w.y; acc2 += xv * w.z; acc3 += xv * w.w;  \
    }
    QSTEP(0, 0x00)
    QSTEP(1, 0x55)
    QSTEP(2, 0xAA)
    QSTEP(3, 0xFF)
#undef QSTEP
    float dv = dinv[v];
    unsigned u0 = f2bf(acc0 * dv) | (f2bf(acc1 * dv) << 16);
    unsigned u1 = f2bf(acc2 * dv) | (f2bf(acc3 * dv) << 16);
    ((uint2*)(g1b + (size_t)v * 8))[q] = make_uint2(u0, u1);
}

// ---------------- layer 1 gather + fused layer-2 transform ----------------
// 8 lanes/node; lane j owns channels 2j,2j+1. After the gather, each lane
// applies relu+b1 and its W2 rows, then 3 shfl_xor reduce -> g2.
__global__ __launch_bounds__(256) void k_gather1mm2(const int* __restrict__ rowstart,
                                                    const int* __restrict__ esrc,
                                                    const float* __restrict__ dinv,
                                                    const unsigned* __restrict__ G,
                                                    const float* __restrict__ b1,
                                                    const float* __restrict__ W2,
                                                    float* __restrict__ g2) {
    int t = blockIdx.x * 256 + threadIdx.x;
    int v = t >> 3;
    int j = t & 7;
    if (v >= NN) return;
    int beg = rowstart[v];
    int end = rowstart[v + 1];
    unsigned a = G[(v << 3) + j];  // self loop
    float c0 = bflo(a), c1 = bfhi(a);
    int p = beg;
    int n4 = beg + ((end - beg) & ~3);
    for (; p < n4; p += 4) {
        int u0 = esrc[p], u1 = esrc[p + 1], u2 = esrc[p + 2], u3 = esrc[p + 3];
        unsigned b0 = G[(u0 << 3) + j];
        unsigned b1w = G[(u1 << 3) + j];
        unsigned b2w = G[(u2 << 3) + j];
        unsigned b3w = G[(u3 << 3) + j];
        c0 += bflo(b0) + bflo(b1w) + bflo(b2w) + bflo(b3w);
        c1 += bfhi(b0) + bfhi(b1w) + bfhi(b2w) + bfhi(b3w);
    }
    for (; p < end; ++p) {
        unsigned b = G[(esrc[p] << 3) + j];
        c0 += bflo(b);
        c1 += bfhi(b);
    }
    float dv = dinv[v];
    // fused mm2: relu(out1 + b1) @ W2, partial over this lane's 2 channels
    float o0 = fmaxf(c0 * dv + b1[2 * j], 0.f);
    float o1 = fmaxf(c1 * dv + b1[2 * j + 1], 0.f);
    float p0 = o0 * W2[(2 * j) * 2 + 0] + o1 * W2[(2 * j + 1) * 2 + 0];
    float p1 = o0 * W2[(2 * j) * 2 + 1] + o1 * W2[(2 * j + 1) * 2 + 1];
    p0 += __shfl_xor(p0, 1); p0 += __shfl_xor(p0, 2); p0 += __shfl_xor(p0, 4);
    p1 += __shfl_xor(p1, 1); p1 += __shfl_xor(p1, 2); p1 += __shfl_xor(p1, 4);
    if (j == 0) {
        float2 w = make_float2(p0 * dv, p1 * dv);
        *(float2*)(g2 + (size_t)v * 2) = w;
    }
}

// ---------------- layer 2 gather: 8 lanes/node = 4 edge-slots x 2 ch -------
__global__ __launch_bounds__(256) void k_gather2(const int* __restrict__ rowstart,
                                                 const int* __restrict__ esrc,
                                                 const float* __restrict__ dinv,
                                                 const float* __restrict__ g2,
                                                 const float* __restrict__ b2,
                                                 float* __restrict__ out) {
    int t = blockIdx.x * 256 + threadIdx.x;
    int v = t >> 3;
    if (v >= NN) return;
    int lane = t & 7;
    int ch = lane & 1;
    int slot = lane >> 1;
    int beg = rowstart[v];
    int end = rowstart[v + 1];
    float acc = 0.0f;
    for (int p = beg + slot; p < end; p += 4)
        acc += g2[(esrc[p] << 1) + ch];
    acc += __shfl_xor(acc, 2);
    acc += __shfl_xor(acc, 4);  // all slots summed
    float o = (acc + g2[(v << 1) + ch]) * dinv[v] + b2[ch];
    float other = __shfl_xor(o, 1);
    float m = fmaxf(o, other);
    float lse = m + logf(expf(o - m) + expf(other - m));
    if (slot == 0) out[(v << 1) + ch] = o - lse;
}

extern "C" void kernel_launch(void* const* d_in, const int* in_sizes, int n_in,
                              void* d_out, int out_size, void* d_ws, size_t ws_size,
                              hipStream_t stream) {
    const float* x  = (const float*)d_in[0];
    const float* W1 = (const float*)d_in[1];
    const float* b1 = (const float*)d_in[2];
    const float* W2 = (const float*)d_in[3];
    const float* b2 = (const float*)d_in[4];
    const int* ei   = (const int*)d_in[5];
    const int* src = ei;
    const int* dst = ei + NE;

    // workspace (4B elems). packed (NE=12.8MB) is dead after k_pass2;
    // g1b (8NN uints = 3.2MB) aliases it. Stream order makes this safe.
    int* ws       = (int*)d_ws;
    int* bcount   = ws;                    // 400
    int* bstart   = ws + 400;              // 400 (uses NBUCK+1)
    int* bcursor  = ws + 800;              // 400
    int* rowstart = ws + 1200;             // NN+16
    float* dinv   = (float*)(ws + 1200 + NN + 16);    // NN
    int* esrc     = ws + 1200 + 2 * NN + 16;          // NE
    unsigned* packed = (unsigned*)(esrc + NE);        // NE
    unsigned* g1b = packed;                // 8*NN uints (aliases packed)
    float* g2     = (float*)(packed + NE); // 2*NN

    float* out = (float*)d_out;

    k_zero_b<<<1, 512, 0, stream>>>(bcount);
    k_bhist<<<NBB, BHT, 0, stream>>>(dst, bcount);
    k_bscan<<<1, 512, 0, stream>>>(bcount, bstart, bcursor);
    k_bfill<<<NBB, BHT, 0, stream>>>(src, dst, bcursor, packed);
    k_pass2<<<NBUCK, 256, 0, stream>>>(bstart, packed, rowstart, dinv, esrc);
    k_mm1<<<(NN * 4 + 255) / 256, 256, 0, stream>>>(x, W1, dinv, g1b);
    k_gather1mm2<<<(NN * 8 + 255) / 256, 256, 0, stream>>>(rowstart, esrc, dinv, g1b, b1, W2, g2);
    k_gather2<<<(NN * 8 + 255) / 256, 256, 0, stream>>>(rowstart, esrc, dinv, g2, b2, out);
}